// Round 3
// baseline (1359.569 us; speedup 1.0000x reference)
//
#include <hip/hip_runtime.h>
#include <cstdint>
#include <cstddef>

// ---------- types ----------
typedef _Float16 half2v __attribute__((ext_vector_type(2)));
typedef _Float16 half4v __attribute__((ext_vector_type(4)));
typedef _Float16 half8v __attribute__((ext_vector_type(8)));
typedef float f32x4 __attribute__((ext_vector_type(4)));

#if __has_builtin(__builtin_amdgcn_fdot2)
#define FDOT2(a, b, c) __builtin_amdgcn_fdot2((a), (b), (c), false)
#else
static __device__ __forceinline__ float fdot2_fb(half2v a, half2v b, float c) {
    return c + (float)a[0] * (float)b[0] + (float)a[1] * (float)b[1];
}
#define FDOT2(a, b, c) fdot2_fb((a), (b), (c))
#endif

__device__ __forceinline__ float sigm(float x) { return 1.0f / (1.0f + __expf(-x)); }
__device__ __forceinline__ float tanh_(float x) { return 1.0f - 2.0f / (__expf(2.0f * x) + 1.0f); }

// Problem constants
#define BB 128
#define TT 512
#define II 300
#define HH 256
#define GG 1024  // 4*H

// ============================================================================
// Kernel 1: xp GEMM.  XP[m][n] = sum_k X[m][k]*W[n][k] + bias[n]
// M = B*T = 65536, K = 300 (padded to 320), N = 1024. 128x128 tile / 256 thr.
// ============================================================================
__global__ __launch_bounds__(256, 3) void gemm_xp(
    const float* __restrict__ X, const float* __restrict__ W,
    const float* __restrict__ bias, _Float16* __restrict__ XP)
{
    __shared__ _Float16 As[128 * 32];
    __shared__ _Float16 Bs[128 * 32];

    const int t = threadIdx.x;
    const int m0 = blockIdx.y * 128;
    const int n0 = blockIdx.x * 128;
    const int kpos = t & 7;
    const int rbase = t >> 3;
    const int lane = t & 63;
    const int wv = t >> 6;
    const int mq = (wv >> 1) * 4;
    const int nq = (wv & 1) * 4;

    f32x4 acc[4][4];
#pragma unroll
    for (int i = 0; i < 4; ++i)
#pragma unroll
        for (int j = 0; j < 4; ++j) acc[i][j] = f32x4{0.f, 0.f, 0.f, 0.f};

    for (int kc = 0; kc < 320; kc += 32) {
        __syncthreads();
        const int k0 = kc + kpos * 4;
#pragma unroll
        for (int rr = 0; rr < 4; ++rr) {
            const int row = rbase + rr * 32;
            float4 va = {0.f, 0.f, 0.f, 0.f}, vb = {0.f, 0.f, 0.f, 0.f};
            if (k0 < 300) {
                va = *(const float4*)(X + (size_t)(m0 + row) * II + k0);
                vb = *(const float4*)(W + (size_t)(n0 + row) * II + k0);
            }
            const int idx = (row >> 4) * 512 + (kpos >> 1) * 128 + (row & 15) * 8 + (kpos & 1) * 4;
            half4v ha = {(_Float16)va.x, (_Float16)va.y, (_Float16)va.z, (_Float16)va.w};
            half4v hb = {(_Float16)vb.x, (_Float16)vb.y, (_Float16)vb.z, (_Float16)vb.w};
            *(half4v*)(&As[idx]) = ha;
            *(half4v*)(&Bs[idx]) = hb;
        }
        __syncthreads();

        half8v af[4], bf[4];
#pragma unroll
        for (int i = 0; i < 4; ++i) {
            af[i] = *(const half8v*)(&As[(mq + i) * 512 + (lane >> 4) * 128 + (lane & 15) * 8]);
            bf[i] = *(const half8v*)(&Bs[(nq + i) * 512 + (lane >> 4) * 128 + (lane & 15) * 8]);
        }
#pragma unroll
        for (int i = 0; i < 4; ++i)
#pragma unroll
            for (int j = 0; j < 4; ++j)
                acc[i][j] = __builtin_amdgcn_mfma_f32_16x16x32_f16(af[i], bf[j], acc[i][j], 0, 0, 0);
    }

#pragma unroll
    for (int j = 0; j < 4; ++j) {
        const int n = n0 + (nq + j) * 16 + (lane & 15);
        const float bv = bias[n];
#pragma unroll
        for (int i = 0; i < 4; ++i) {
#pragma unroll
            for (int r = 0; r < 4; ++r) {
                const int m = m0 + (mq + i) * 16 + (lane >> 4) * 4 + r;
                XP[(size_t)m * GG + n] = (_Float16)(acc[i][j][r] + bv);
            }
        }
    }
}

// ============================================================================
// Kernel 2: forward recurrence. One WG (512 thr) per batch element.
// Thread t owns gate rows (t, t+512): t<256 -> (i[j], g[j]); t>=256 -> (f[j], o[j]),
// j = t & 255. Weights: k in [0,192) resident as 192 VGPRs of half2;
// k in [192,256) in 128 KB LDS. Exchange preacts with partner t^256; ALL
// threads compute c,h (c replicated) -> no half-idle tail. xp prefetched
// one step ahead. c,h fp32; weights/h fp16.
// ============================================================================
__global__ __launch_bounds__(512, 2) void lstm_fwd(
    const float* __restrict__ Whh, const _Float16* __restrict__ XP,
    float* __restrict__ HF)
{
    __shared__ _Float16 wlds[8 * GG * 8];         // 128 KB: [grp][gate][8]
    __shared__ float glds[GG];                    // 4 KB
    __shared__ __align__(16) _Float16 hlds[HH];   // 512 B

    const int t = threadIdx.x;
    const int b = blockIdx.x;
    const int r1 = t + 512;

    // ---- resident weights: k = 0..191 for both gate rows (192 VGPRs) ----
    half2v w0[96], w1[96];
#pragma unroll
    for (int i = 0; i < 48; ++i) {
        float4 v = *(const float4*)(Whh + (size_t)t * HH + i * 4);
        w0[2 * i]     = half2v{(_Float16)v.x, (_Float16)v.y};
        w0[2 * i + 1] = half2v{(_Float16)v.z, (_Float16)v.w};
    }
#pragma unroll
    for (int i = 0; i < 48; ++i) {
        float4 v = *(const float4*)(Whh + (size_t)r1 * HH + i * 4);
        w1[2 * i]     = half2v{(_Float16)v.x, (_Float16)v.y};
        w1[2 * i + 1] = half2v{(_Float16)v.z, (_Float16)v.w};
    }
    // ---- LDS weights: k = 192..255 for both gate rows ----
#pragma unroll
    for (int grp = 0; grp < 8; ++grp) {
        float4 a  = *(const float4*)(Whh + (size_t)t * HH + 192 + grp * 8);
        float4 c4 = *(const float4*)(Whh + (size_t)t * HH + 192 + grp * 8 + 4);
        half8v hv = {(_Float16)a.x, (_Float16)a.y, (_Float16)a.z, (_Float16)a.w,
                     (_Float16)c4.x, (_Float16)c4.y, (_Float16)c4.z, (_Float16)c4.w};
        *(half8v*)(&wlds[grp * (GG * 8) + t * 8]) = hv;
        float4 a2 = *(const float4*)(Whh + (size_t)r1 * HH + 192 + grp * 8);
        float4 c2 = *(const float4*)(Whh + (size_t)r1 * HH + 192 + grp * 8 + 4);
        half8v hv2 = {(_Float16)a2.x, (_Float16)a2.y, (_Float16)a2.z, (_Float16)a2.w,
                      (_Float16)c2.x, (_Float16)c2.y, (_Float16)c2.z, (_Float16)c2.w};
        *(half8v*)(&wlds[grp * (GG * 8) + r1 * 8]) = hv2;
    }
    if (t < HH) hlds[t] = (_Float16)0.f;
    float c = 0.0f;
    __syncthreads();

    const _Float16* xp_b = XP + (size_t)b * TT * GG;
    _Float16 x0 = xp_b[t];
    _Float16 x1 = xp_b[r1];

    for (int ts = 0; ts < TT; ++ts) {
        // prefetch next step's xp (full step of latency to land)
        const _Float16* xp_n = xp_b + ((ts < TT - 1) ? GG : 0);
        const _Float16 nx0 = xp_n[t];
        const _Float16 nx1 = xp_n[r1];

        float a0 = 0.f, a1 = 0.f;
#pragma unroll
        for (int cq = 0; cq < 24; ++cq) {  // k = 0..191 from VGPR weights
            half8v hv = *(const half8v*)(&hlds[cq * 8]);
            half2v h0 = __builtin_shufflevector(hv, hv, 0, 1);
            half2v h1 = __builtin_shufflevector(hv, hv, 2, 3);
            half2v h2 = __builtin_shufflevector(hv, hv, 4, 5);
            half2v h3 = __builtin_shufflevector(hv, hv, 6, 7);
            a0 = FDOT2(h0, w0[cq * 4 + 0], a0);
            a1 = FDOT2(h0, w1[cq * 4 + 0], a1);
            a0 = FDOT2(h1, w0[cq * 4 + 1], a0);
            a1 = FDOT2(h1, w1[cq * 4 + 1], a1);
            a0 = FDOT2(h2, w0[cq * 4 + 2], a0);
            a1 = FDOT2(h2, w1[cq * 4 + 2], a1);
            a0 = FDOT2(h3, w0[cq * 4 + 3], a0);
            a1 = FDOT2(h3, w1[cq * 4 + 3], a1);
        }
#define LDS_W_STEP(W_IDX, I0, I1)                                          \
        {                                                                  \
            half2v hp  = __builtin_shufflevector(hv, hv, I0, I1);          \
            half2v wap = __builtin_shufflevector(wa, wa, I0, I1);          \
            half2v wbp = __builtin_shufflevector(wb, wb, I0, I1);          \
            a0 = FDOT2(hp, wap, a0);                                       \
            a1 = FDOT2(hp, wbp, a1);                                       \
        }
#pragma unroll
        for (int grp = 0; grp < 8; ++grp) {  // k = 192..255 from LDS weights
            half8v hv = *(const half8v*)(&hlds[192 + grp * 8]);
            half8v wa = *(const half8v*)(&wlds[grp * (GG * 8) + t * 8]);
            half8v wb = *(const half8v*)(&wlds[grp * (GG * 8) + r1 * 8]);
            LDS_W_STEP(0, 0, 1)
            LDS_W_STEP(1, 2, 3)
            LDS_W_STEP(2, 4, 5)
            LDS_W_STEP(3, 6, 7)
        }
#undef LDS_W_STEP
        const float o0 = a0 + (float)x0;
        const float o1 = a1 + (float)x1;
        glds[t] = o0;
        glds[t + 512] = o1;
        __syncthreads();
        // partner exchange: t<256 owns (i,g), partner t^256 has (f,o)
        const float p0 = glds[t ^ 256];
        const float p1 = glds[(t ^ 256) + 512];
        const float gi = (t < 256) ? o0 : p0;
        const float gg = (t < 256) ? o1 : p1;
        const float gf = (t < 256) ? p0 : o0;
        const float go = (t < 256) ? p1 : o1;
        c = sigm(gf) * c + sigm(gi) * tanh_(gg);
        const float h = sigm(go) * tanh_(c);
        if (t < HH) {
            hlds[t] = (_Float16)h;
            if (ts == TT - 1) HF[(size_t)b * HH + t] = h;
        }
        __syncthreads();

        x0 = nx0;
        x1 = nx1;
        xp_b = xp_n;
    }
}

// ============================================================================
// Kernel 3: backward direction = ONE cell step on x[:, T-1] with h0=c0=0.
// ============================================================================
__global__ __launch_bounds__(256) void lstm_bwd(
    const float* __restrict__ X, const float* __restrict__ Wih,
    const float* __restrict__ bb, float* __restrict__ HB)
{
    __shared__ float xs[II];
    const int b = blockIdx.x, t = threadIdx.x;
    const float* xrow = X + ((size_t)b * TT + (TT - 1)) * II;
    if (t < 75) *(float4*)(&xs[t * 4]) = *(const float4*)(xrow + t * 4);
    __syncthreads();
    if (t < HH) {
        float ai = 0.f, ag = 0.f, ao = 0.f;
        const float4* wi = (const float4*)(Wih + (size_t)t * II);
        const float4* wg = (const float4*)(Wih + (size_t)(t + 512) * II);
        const float4* wo = (const float4*)(Wih + (size_t)(t + 768) * II);
        for (int k4 = 0; k4 < 75; ++k4) {
            float4 xv = *(const float4*)(&xs[k4 * 4]);
            float4 a = wi[k4], g4 = wg[k4], o4 = wo[k4];
            ai += xv.x * a.x + xv.y * a.y + xv.z * a.z + xv.w * a.w;
            ag += xv.x * g4.x + xv.y * g4.y + xv.z * g4.z + xv.w * g4.w;
            ao += xv.x * o4.x + xv.y * o4.y + xv.z * o4.z + xv.w * o4.w;
        }
        ai += bb[t];
        ag += bb[t + 512];
        ao += bb[t + 768];
        const float cg = sigm(ai) * tanh_(ag);
        HB[(size_t)b * HH + t] = sigm(ao) * tanh_(cg);
    }
}

// ============================================================================
// Kernel 4: out[b][jj] = [hf|hb] . W_lin[jj] + b_lin[jj]
// ============================================================================
__global__ __launch_bounds__(256) void final_k(
    const float* __restrict__ HF, const float* __restrict__ HB,
    const float* __restrict__ Wlin, const float* __restrict__ blin,
    float* __restrict__ OUT)
{
    const int t = threadIdx.x;
    const int b = t >> 1, jj = t & 1;
    float acc = blin[jj];
    const float* wf = Wlin + jj * 512;
    const float* wb = Wlin + jj * 512 + 256;
    const float* hf = HF + (size_t)b * HH;
    const float* hb = HB + (size_t)b * HH;
    for (int k = 0; k < HH; k += 4) {
        float4 h4 = *(const float4*)(hf + k);
        float4 w4 = *(const float4*)(wf + k);
        float4 g4 = *(const float4*)(hb + k);
        float4 v4 = *(const float4*)(wb + k);
        acc += h4.x * w4.x + h4.y * w4.y + h4.z * w4.z + h4.w * w4.w;
        acc += g4.x * v4.x + g4.y * v4.y + g4.z * v4.z + g4.w * v4.w;
    }
    OUT[b * 2 + jj] = acc;
}

// ============================================================================
extern "C" void kernel_launch(void* const* d_in, const int* in_sizes, int n_in,
                              void* d_out, int out_size, void* d_ws, size_t ws_size,
                              hipStream_t stream)
{
    const float* x = (const float*)d_in[0];
    const float* Wihf = (const float*)d_in[1];
    const float* Whhf = (const float*)d_in[2];
    const float* bf = (const float*)d_in[3];
    const float* Wihb = (const float*)d_in[4];
    const float* Whhb = (const float*)d_in[5];
    const float* bbv = (const float*)d_in[6];
    const float* Wlin = (const float*)d_in[7];
    const float* blin = (const float*)d_in[8];
    float* out = (float*)d_out;
    (void)Whhb; (void)in_sizes; (void)n_in; (void)out_size; (void)ws_size;

    // workspace: xp fp16 (134,217,728 B) | hf f32 | hb f32
    _Float16* xp = (_Float16*)d_ws;
    float* hf = (float*)((char*)d_ws + (size_t)BB * TT * GG * 2);
    float* hb = hf + (size_t)BB * HH;

    lstm_bwd<<<BB, 256, 0, stream>>>(x, Wihb, bbv, hb);
    gemm_xp<<<dim3(GG / 128, (BB * TT) / 128), 256, 0, stream>>>(x, Wihf, bf, xp);
    lstm_fwd<<<BB, 512, 0, stream>>>(Whhf, xp, hf);
    final_k<<<1, 256, 0, stream>>>(hf, hb, Wlin, blin, out);
}

// Round 4
// 1317.329 us; speedup vs baseline: 1.0321x; 1.0321x over previous
//
#include <hip/hip_runtime.h>
#include <cstdint>
#include <cstddef>

// ---------- types ----------
typedef _Float16 half2v __attribute__((ext_vector_type(2)));
typedef _Float16 half4v __attribute__((ext_vector_type(4)));
typedef _Float16 half8v __attribute__((ext_vector_type(8)));
typedef float f32x4 __attribute__((ext_vector_type(4)));

#if __has_builtin(__builtin_amdgcn_fdot2)
#define FDOT2(a, b, c) __builtin_amdgcn_fdot2((a), (b), (c), false)
#else
static __device__ __forceinline__ float fdot2_fb(half2v a, half2v b, float c) {
    return c + (float)a[0] * (float)b[0] + (float)a[1] * (float)b[1];
}
#define FDOT2(a, b, c) fdot2_fb((a), (b), (c))
#endif

__device__ __forceinline__ float sigm(float x) { return 1.0f / (1.0f + __expf(-x)); }
__device__ __forceinline__ float tanh_(float x) { return 1.0f - 2.0f / (__expf(2.0f * x) + 1.0f); }

// Problem constants
#define BB 128
#define TT 512
#define II 300
#define HH 256
#define GG 1024  // 4*H

// ============================================================================
// Kernel 1: xp GEMM.  XP[m][n] = sum_k X[m][k]*W[n][k] + bias[n]
// M = B*T = 65536, K = 300 (padded to 320), N = 1024. 128x128 tile / 256 thr.
// ============================================================================
__global__ __launch_bounds__(256, 3) void gemm_xp(
    const float* __restrict__ X, const float* __restrict__ W,
    const float* __restrict__ bias, _Float16* __restrict__ XP)
{
    __shared__ _Float16 As[128 * 32];
    __shared__ _Float16 Bs[128 * 32];

    const int t = threadIdx.x;
    const int m0 = blockIdx.y * 128;
    const int n0 = blockIdx.x * 128;
    const int kpos = t & 7;
    const int rbase = t >> 3;
    const int lane = t & 63;
    const int wv = t >> 6;
    const int mq = (wv >> 1) * 4;
    const int nq = (wv & 1) * 4;

    f32x4 acc[4][4];
#pragma unroll
    for (int i = 0; i < 4; ++i)
#pragma unroll
        for (int j = 0; j < 4; ++j) acc[i][j] = f32x4{0.f, 0.f, 0.f, 0.f};

    for (int kc = 0; kc < 320; kc += 32) {
        __syncthreads();
        const int k0 = kc + kpos * 4;
#pragma unroll
        for (int rr = 0; rr < 4; ++rr) {
            const int row = rbase + rr * 32;
            float4 va = {0.f, 0.f, 0.f, 0.f}, vb = {0.f, 0.f, 0.f, 0.f};
            if (k0 < 300) {
                va = *(const float4*)(X + (size_t)(m0 + row) * II + k0);
                vb = *(const float4*)(W + (size_t)(n0 + row) * II + k0);
            }
            const int idx = (row >> 4) * 512 + (kpos >> 1) * 128 + (row & 15) * 8 + (kpos & 1) * 4;
            half4v ha = {(_Float16)va.x, (_Float16)va.y, (_Float16)va.z, (_Float16)va.w};
            half4v hb = {(_Float16)vb.x, (_Float16)vb.y, (_Float16)vb.z, (_Float16)vb.w};
            *(half4v*)(&As[idx]) = ha;
            *(half4v*)(&Bs[idx]) = hb;
        }
        __syncthreads();

        half8v af[4], bf[4];
#pragma unroll
        for (int i = 0; i < 4; ++i) {
            af[i] = *(const half8v*)(&As[(mq + i) * 512 + (lane >> 4) * 128 + (lane & 15) * 8]);
            bf[i] = *(const half8v*)(&Bs[(nq + i) * 512 + (lane >> 4) * 128 + (lane & 15) * 8]);
        }
#pragma unroll
        for (int i = 0; i < 4; ++i)
#pragma unroll
            for (int j = 0; j < 4; ++j)
                acc[i][j] = __builtin_amdgcn_mfma_f32_16x16x32_f16(af[i], bf[j], acc[i][j], 0, 0, 0);
    }

#pragma unroll
    for (int j = 0; j < 4; ++j) {
        const int n = n0 + (nq + j) * 16 + (lane & 15);
        const float bv = bias[n];
#pragma unroll
        for (int i = 0; i < 4; ++i) {
#pragma unroll
            for (int r = 0; r < 4; ++r) {
                const int m = m0 + (mq + i) * 16 + (lane >> 4) * 4 + r;
                XP[(size_t)m * GG + n] = (_Float16)(acc[i][j][r] + bv);
            }
        }
    }
}

// ============================================================================
// Kernel 2: forward recurrence. One WG (512 thr) per batch element.
// Row mapping (partner-in-wave): wave wv, lane l; j = wv*32 + (l&31).
//   l<32  -> rows (i_j, g_j) = (j,     j+512)
//   l>=32 -> rows (f_j, o_j) = (j+256, j+768)
// Preact exchange via __shfl_xor(.,32) (same wave, no barrier); c,h computed
// redundantly by the pair. h ping-pongs between 2 LDS buffers -> ONE barrier
// per step. Weights: k in [0,192) resident (192 VGPRs of half2, forced by
// amdgpu_waves_per_eu(2,2) -> 256-reg budget); k in [192,256) in 128 KB LDS.
// ============================================================================
__global__ __attribute__((amdgpu_flat_work_group_size(512, 512), amdgpu_waves_per_eu(2, 2)))
void lstm_fwd(
    const float* __restrict__ Whh, const _Float16* __restrict__ XP,
    float* __restrict__ HF)
{
    __shared__ _Float16 wlds[8 * GG * 8];            // 128 KB: [grp][row][8]
    __shared__ __align__(16) _Float16 hlds[2][HH];   // 1 KB ping-pong

    const int t = threadIdx.x;
    const int b = blockIdx.x;
    const int l = t & 63;
    const int wv = t >> 6;
    const int half = l >> 5;               // 0: (i,g) rows, 1: (f,o) rows
    const int j = wv * 32 + (l & 31);      // gate index 0..255
    const int row0 = j + (half ? 256 : 0); // i_j or f_j
    const int row1 = row0 + 512;           // g_j or o_j

    // ---- resident weights: k = 0..191 for both owned rows (192 VGPRs) ----
    half2v w0[96], w1[96];
#pragma unroll
    for (int i = 0; i < 48; ++i) {
        float4 v = *(const float4*)(Whh + (size_t)row0 * HH + i * 4);
        w0[2 * i]     = half2v{(_Float16)v.x, (_Float16)v.y};
        w0[2 * i + 1] = half2v{(_Float16)v.z, (_Float16)v.w};
    }
#pragma unroll
    for (int i = 0; i < 48; ++i) {
        float4 v = *(const float4*)(Whh + (size_t)row1 * HH + i * 4);
        w1[2 * i]     = half2v{(_Float16)v.x, (_Float16)v.y};
        w1[2 * i + 1] = half2v{(_Float16)v.z, (_Float16)v.w};
    }
    // ---- LDS weights: k = 192..255, filled by row index t and t+512 ----
#pragma unroll
    for (int grp = 0; grp < 8; ++grp) {
        float4 a  = *(const float4*)(Whh + (size_t)t * HH + 192 + grp * 8);
        float4 c4 = *(const float4*)(Whh + (size_t)t * HH + 192 + grp * 8 + 4);
        half8v hv = {(_Float16)a.x, (_Float16)a.y, (_Float16)a.z, (_Float16)a.w,
                     (_Float16)c4.x, (_Float16)c4.y, (_Float16)c4.z, (_Float16)c4.w};
        *(half8v*)(&wlds[grp * (GG * 8) + t * 8]) = hv;
        float4 a2 = *(const float4*)(Whh + (size_t)(t + 512) * HH + 192 + grp * 8);
        float4 c2 = *(const float4*)(Whh + (size_t)(t + 512) * HH + 192 + grp * 8 + 4);
        half8v hv2 = {(_Float16)a2.x, (_Float16)a2.y, (_Float16)a2.z, (_Float16)a2.w,
                      (_Float16)c2.x, (_Float16)c2.y, (_Float16)c2.z, (_Float16)c2.w};
        *(half8v*)(&wlds[grp * (GG * 8) + (t + 512) * 8]) = hv2;
    }
    if (t < HH) hlds[0][t] = (_Float16)0.f;
    float c = 0.0f;
    __syncthreads();

    const _Float16* xp_b = XP + (size_t)b * TT * GG;
    _Float16 x0 = xp_b[row0];
    _Float16 x1 = xp_b[row1];

    for (int ts = 0; ts < TT; ++ts) {
        const int p = ts & 1;
        const _Float16* hrd = &hlds[p][0];
        // prefetch next step's xp (full step of latency to land)
        const _Float16* xp_n = xp_b + ((ts < TT - 1) ? GG : 0);
        const _Float16 nx0 = xp_n[row0];
        const _Float16 nx1 = xp_n[row1];

        float a0 = 0.f, a1 = 0.f;
#pragma unroll
        for (int cq = 0; cq < 24; ++cq) {  // k = 0..191 from VGPR weights
            half8v hv = *(const half8v*)(&hrd[cq * 8]);
            half2v h0 = __builtin_shufflevector(hv, hv, 0, 1);
            half2v h1 = __builtin_shufflevector(hv, hv, 2, 3);
            half2v h2 = __builtin_shufflevector(hv, hv, 4, 5);
            half2v h3 = __builtin_shufflevector(hv, hv, 6, 7);
            a0 = FDOT2(h0, w0[cq * 4 + 0], a0);
            a1 = FDOT2(h0, w1[cq * 4 + 0], a1);
            a0 = FDOT2(h1, w0[cq * 4 + 1], a0);
            a1 = FDOT2(h1, w1[cq * 4 + 1], a1);
            a0 = FDOT2(h2, w0[cq * 4 + 2], a0);
            a1 = FDOT2(h2, w1[cq * 4 + 2], a1);
            a0 = FDOT2(h3, w0[cq * 4 + 3], a0);
            a1 = FDOT2(h3, w1[cq * 4 + 3], a1);
        }
#define LDS_W_STEP(I0, I1)                                                 \
        {                                                                  \
            half2v hp  = __builtin_shufflevector(hv, hv, I0, I1);          \
            half2v wap = __builtin_shufflevector(wa, wa, I0, I1);          \
            half2v wbp = __builtin_shufflevector(wb, wb, I0, I1);          \
            a0 = FDOT2(hp, wap, a0);                                       \
            a1 = FDOT2(hp, wbp, a1);                                       \
        }
#pragma unroll
        for (int grp = 0; grp < 8; ++grp) {  // k = 192..255 from LDS weights
            half8v hv = *(const half8v*)(&hrd[192 + grp * 8]);
            half8v wa = *(const half8v*)(&wlds[grp * (GG * 8) + row0 * 8]);
            half8v wb = *(const half8v*)(&wlds[grp * (GG * 8) + row1 * 8]);
            LDS_W_STEP(0, 1)
            LDS_W_STEP(2, 3)
            LDS_W_STEP(4, 5)
            LDS_W_STEP(6, 7)
        }
#undef LDS_W_STEP
        const float o0 = a0 + (float)x0;
        const float o1 = a1 + (float)x1;
        // partner exchange within the wave (lanes l <-> l^32)
        const float p0 = __shfl_xor(o0, 32, 64);
        const float p1 = __shfl_xor(o1, 32, 64);
        const float gi = half ? p0 : o0;
        const float gg = half ? p1 : o1;
        const float gf = half ? o0 : p0;
        const float go = half ? o1 : p1;
        c = sigm(gf) * c + sigm(gi) * tanh_(gg);
        const float h = sigm(go) * tanh_(c);
        if (!half) {
            hlds[p ^ 1][j] = (_Float16)h;
            if (ts == TT - 1) HF[(size_t)b * HH + j] = h;
        }
        __syncthreads();

        x0 = nx0;
        x1 = nx1;
        xp_b = xp_n;
    }
}

// ============================================================================
// Kernel 3: backward direction = ONE cell step on x[:, T-1] with h0=c0=0.
// ============================================================================
__global__ __launch_bounds__(256) void lstm_bwd(
    const float* __restrict__ X, const float* __restrict__ Wih,
    const float* __restrict__ bb, float* __restrict__ HB)
{
    __shared__ float xs[II];
    const int b = blockIdx.x, t = threadIdx.x;
    const float* xrow = X + ((size_t)b * TT + (TT - 1)) * II;
    if (t < 75) *(float4*)(&xs[t * 4]) = *(const float4*)(xrow + t * 4);
    __syncthreads();
    if (t < HH) {
        float ai = 0.f, ag = 0.f, ao = 0.f;
        const float4* wi = (const float4*)(Wih + (size_t)t * II);
        const float4* wg = (const float4*)(Wih + (size_t)(t + 512) * II);
        const float4* wo = (const float4*)(Wih + (size_t)(t + 768) * II);
        for (int k4 = 0; k4 < 75; ++k4) {
            float4 xv = *(const float4*)(&xs[k4 * 4]);
            float4 a = wi[k4], g4 = wg[k4], o4 = wo[k4];
            ai += xv.x * a.x + xv.y * a.y + xv.z * a.z + xv.w * a.w;
            ag += xv.x * g4.x + xv.y * g4.y + xv.z * g4.z + xv.w * g4.w;
            ao += xv.x * o4.x + xv.y * o4.y + xv.z * o4.z + xv.w * o4.w;
        }
        ai += bb[t];
        ag += bb[t + 512];
        ao += bb[t + 768];
        const float cg = sigm(ai) * tanh_(ag);
        HB[(size_t)b * HH + t] = sigm(ao) * tanh_(cg);
    }
}

// ============================================================================
// Kernel 4: out[b][jj] = [hf|hb] . W_lin[jj] + b_lin[jj]
// ============================================================================
__global__ __launch_bounds__(256) void final_k(
    const float* __restrict__ HF, const float* __restrict__ HB,
    const float* __restrict__ Wlin, const float* __restrict__ blin,
    float* __restrict__ OUT)
{
    const int t = threadIdx.x;
    const int b = t >> 1, jj = t & 1;
    float acc = blin[jj];
    const float* wf = Wlin + jj * 512;
    const float* wb = Wlin + jj * 512 + 256;
    const float* hf = HF + (size_t)b * HH;
    const float* hb = HB + (size_t)b * HH;
    for (int k = 0; k < HH; k += 4) {
        float4 h4 = *(const float4*)(hf + k);
        float4 w4 = *(const float4*)(wf + k);
        float4 g4 = *(const float4*)(hb + k);
        float4 v4 = *(const float4*)(wb + k);
        acc += h4.x * w4.x + h4.y * w4.y + h4.z * w4.z + h4.w * w4.w;
        acc += g4.x * v4.x + g4.y * v4.y + g4.z * v4.z + g4.w * v4.w;
    }
    OUT[b * 2 + jj] = acc;
}

// ============================================================================
extern "C" void kernel_launch(void* const* d_in, const int* in_sizes, int n_in,
                              void* d_out, int out_size, void* d_ws, size_t ws_size,
                              hipStream_t stream)
{
    const float* x = (const float*)d_in[0];
    const float* Wihf = (const float*)d_in[1];
    const float* Whhf = (const float*)d_in[2];
    const float* bf = (const float*)d_in[3];
    const float* Wihb = (const float*)d_in[4];
    const float* Whhb = (const float*)d_in[5];
    const float* bbv = (const float*)d_in[6];
    const float* Wlin = (const float*)d_in[7];
    const float* blin = (const float*)d_in[8];
    float* out = (float*)d_out;
    (void)Whhb; (void)in_sizes; (void)n_in; (void)out_size; (void)ws_size;

    // workspace: xp fp16 (134,217,728 B) | hf f32 | hb f32
    _Float16* xp = (_Float16*)d_ws;
    float* hf = (float*)((char*)d_ws + (size_t)BB * TT * GG * 2);
    float* hb = hf + (size_t)BB * HH;

    lstm_bwd<<<BB, 256, 0, stream>>>(x, Wihb, bbv, hb);
    gemm_xp<<<dim3(GG / 128, (BB * TT) / 128), 256, 0, stream>>>(x, Wihf, bf, xp);
    lstm_fwd<<<BB, 512, 0, stream>>>(Whhf, xp, hf);
    final_k<<<1, 256, 0, stream>>>(hf, hb, Wlin, blin, out);
}